// Round 5
// baseline (132.249 us; speedup 1.0000x reference)
//
#include <hip/hip_runtime.h>
#include <hip/hip_bf16.h>
#include <math.h>

#define SS 2048
#define HH 16
#define DD 128
#define HD (HH*DD)
#define QBLK 64
#define KVBLK 64

typedef __attribute__((ext_vector_type(8))) short bf16x8;
typedef __attribute__((ext_vector_type(4))) float f32x4;

#define EXP2(x) exp2f(x)

__device__ __forceinline__ ushort f2bf(float f) {
  __hip_bfloat16 h = __float2bfloat16(f);
  return __builtin_bit_cast(ushort, h);
}

// ---------------------------------------------------------------------------
// Prep: K fp32 [t][h][d] -> bf16 Kbf [h][t][d];  V fp32 -> bf16 VTg [h][d][t]
// ---------------------------------------------------------------------------
__global__ __launch_bounds__(256, 4)
void prep_kv(const float* __restrict__ K, const float* __restrict__ V,
             ushort* __restrict__ Kbf, ushort* __restrict__ VTg) {
  __shared__ ushort Vlds[64][136];
  const int tid = threadIdx.x;
  const int h  = blockIdx.x & 15;
  const int t0 = (blockIdx.x >> 4) * 64;

  // K: streaming convert, coalesced in and out
  #pragma unroll
  for (int j = 0; j < 2; ++j) {
    int li = tid + j * 256;
    int t  = li >> 3;
    int c  = (li & 7) << 4;
    const float* src = K + ((size_t)(t0 + t) * HH + h) * DD + c;
    ushort tmp[16];
    #pragma unroll
    for (int q = 0; q < 4; ++q) {
      float4 x = *(const float4*)(src + 4 * q);
      tmp[4*q+0] = f2bf(x.x); tmp[4*q+1] = f2bf(x.y);
      tmp[4*q+2] = f2bf(x.z); tmp[4*q+3] = f2bf(x.w);
    }
    ushort* dst = Kbf + ((size_t)h * SS + t0 + t) * DD + c;
    *(uint4*)dst       = *(uint4*)&tmp[0];
    *(uint4*)(dst + 8) = *(uint4*)&tmp[8];
  }

  // V: load+convert into LDS tile [t][d]
  #pragma unroll
  for (int j = 0; j < 2; ++j) {
    int li = tid + j * 256;
    int t  = li >> 3;
    int c  = (li & 7) << 4;
    const float* src = V + ((size_t)(t0 + t) * HH + h) * DD + c;
    #pragma unroll
    for (int q = 0; q < 4; ++q) {
      float4 x = *(const float4*)(src + 4 * q);
      ushort4 w; w.x = f2bf(x.x); w.y = f2bf(x.y); w.z = f2bf(x.z); w.w = f2bf(x.w);
      *(ushort4*)&Vlds[t][c + 4 * q] = w;
    }
  }
  __syncthreads();

  // transpose out: VT[h][d][t0..t0+63]
  #pragma unroll
  for (int j = 0; j < 2; ++j) {
    int li  = tid + j * 256;
    int d   = li >> 2;
    int t16 = (li & 3) << 4;
    ushort tmp[16];
    #pragma unroll
    for (int k = 0; k < 16; ++k) tmp[k] = Vlds[t16 + k][d];
    ushort* dst = VTg + ((size_t)h * DD + d) * SS + t0 + t16;
    *(uint4*)dst       = *(uint4*)&tmp[0];
    *(uint4*)(dst + 8) = *(uint4*)&tmp[8];
  }
}

// ---------------------------------------------------------------------------
// Flash attention — R2 structure verbatim, staging from prep'd bf16 buffers
// ---------------------------------------------------------------------------
__global__ __launch_bounds__(256, 2)
void attn_fwd(const float* __restrict__ Q, const ushort* __restrict__ Kbf,
              const ushort* __restrict__ VTg, float* __restrict__ O) {
  __shared__ alignas(16) ushort Klds[KVBLK][136];   // 17408 B
  __shared__ alignas(16) ushort VTlds[DD][72];      // 18432 B
  __shared__ alignas(16) ushort Plds[4][16][72];    //  9216 B

  const int tid  = threadIdx.x;
  const int lane = tid & 63;
  const int wid  = tid >> 6;
  const int n    = lane & 15;
  const int g    = lane >> 4;

  const int h  = blockIdx.x & (HH - 1);
  const int j  = blockIdx.x >> 4;
  const int qt = (j < 16) ? (31 - j) : (j - 16);   // pair long+short per CU
  const int qb = qt * QBLK;
  const int qw = qb + 16 * wid;

  const float SCALE = 1.44269504088896f / sqrtf((float)DD);

  // ---- preload Q fragments (A operand), scaled, bf16 ----
  bf16x8 qfrag[4];
  {
    const float* qrow = Q + ((size_t)(qw + n) * HH + h) * DD;
    #pragma unroll
    for (int ks = 0; ks < 4; ++ks) {
      const int d0 = 32 * ks + 8 * g;
      float4 x = *(const float4*)&qrow[d0];
      float4 y = *(const float4*)&qrow[d0 + 4];
      bf16x8 a;
      a[0] = (short)f2bf(x.x * SCALE); a[1] = (short)f2bf(x.y * SCALE);
      a[2] = (short)f2bf(x.z * SCALE); a[3] = (short)f2bf(x.w * SCALE);
      a[4] = (short)f2bf(y.x * SCALE); a[5] = (short)f2bf(y.y * SCALE);
      a[6] = (short)f2bf(y.z * SCALE); a[7] = (short)f2bf(y.w * SCALE);
      qfrag[ks] = a;
    }
  }

  f32x4 acc[8];
  #pragma unroll
  for (int d0 = 0; d0 < 8; ++d0) { acc[d0][0]=0.f; acc[d0][1]=0.f; acc[d0][2]=0.f; acc[d0][3]=0.f; }
  float m[4] = { -INFINITY, -INFINITY, -INFINITY, -INFINITY };
  float l[4] = { 0.f, 0.f, 0.f, 0.f };

  const ushort* Kh  = Kbf + (size_t)h * SS * DD;
  const ushort* VTh = VTg + (size_t)h * DD * SS;
  const int nt = qb / KVBLK + 1;

  uint4 kreg[4], vreg[4];

  // prefetch tile 0
  #pragma unroll
  for (int it = 0; it < 4; ++it) {
    int li = tid + it * 256;
    int kt = li >> 4, kc = (li & 15) << 3;     // K: row t, col c
    kreg[it] = *(const uint4*)(Kh + (size_t)kt * DD + kc);
    int vd = li >> 3, vt = (li & 7) << 3;      // V: row d, col t
    vreg[it] = *(const uint4*)(VTh + (size_t)vd * SS + vt);
  }

  for (int itile = 0; itile < nt; ++itile) {
    __syncthreads();   // previous tile's LDS fully consumed

    // ---- regs -> LDS (pure b128 copies) ----
    #pragma unroll
    for (int it = 0; it < 4; ++it) {
      int li = tid + it * 256;
      int kt = li >> 4, kc = (li & 15) << 3;
      *(uint4*)&Klds[kt][kc] = kreg[it];
      int vd = li >> 3, vt = (li & 7) << 3;
      *(uint4*)&VTlds[vd][vt] = vreg[it];
    }
    __syncthreads();   // tile ready

    // ---- prefetch next tile ----
    if (itile + 1 < nt) {
      const int t0n = (itile + 1) * KVBLK;
      #pragma unroll
      for (int it = 0; it < 4; ++it) {
        int li = tid + it * 256;
        int kt = li >> 4, kc = (li & 15) << 3;
        kreg[it] = *(const uint4*)(Kh + (size_t)(t0n + kt) * DD + kc);
        int vd = li >> 3, vt = (li & 7) << 3;
        vreg[it] = *(const uint4*)(VTh + (size_t)vd * SS + t0n + vt);
      }
    }

    const int t0 = itile * KVBLK;

    // ---- QK^T: S[q][t], 16x64 per wave ----
    f32x4 s[4];
    #pragma unroll
    for (int sub = 0; sub < 4; ++sub) { s[sub][0]=0.f; s[sub][1]=0.f; s[sub][2]=0.f; s[sub][3]=0.f; }
    #pragma unroll
    for (int ks = 0; ks < 4; ++ks) {
      #pragma unroll
      for (int sub = 0; sub < 4; ++sub) {
        bf16x8 b = *(const bf16x8*)&Klds[sub * 16 + n][32 * ks + 8 * g];
        s[sub] = __builtin_amdgcn_mfma_f32_16x16x32_bf16(qfrag[ks], b, s[sub], 0, 0, 0);
      }
    }

    // ---- causal mask (diagonal tiles only) ----
    if (t0 + KVBLK - 1 > qw) {
      #pragma unroll
      for (int sub = 0; sub < 4; ++sub) {
        int tg = t0 + sub * 16 + n;
        #pragma unroll
        for (int r = 0; r < 4; ++r) {
          int qg = qw + 4 * g + r;
          if (tg > qg) s[sub][r] = -INFINITY;
        }
      }
    }

    // ---- online softmax (log2 domain) ----
    float mr[4];
    #pragma unroll
    for (int r = 0; r < 4; ++r)
      mr[r] = fmaxf(fmaxf(s[0][r], s[1][r]), fmaxf(s[2][r], s[3][r]));
    #pragma unroll
    for (int off = 1; off <= 8; off <<= 1) {
      #pragma unroll
      for (int r = 0; r < 4; ++r)
        mr[r] = fmaxf(mr[r], __shfl_xor(mr[r], off));
    }
    float corr[4];
    #pragma unroll
    for (int r = 0; r < 4; ++r) {
      float mn = fmaxf(m[r], mr[r]);
      corr[r] = EXP2(m[r] - mn);
      m[r] = mn;
    }
    float sr[4] = { 0.f, 0.f, 0.f, 0.f };
    #pragma unroll
    for (int sub = 0; sub < 4; ++sub) {
      #pragma unroll
      for (int r = 0; r < 4; ++r) {
        float p = EXP2(s[sub][r] - m[r]);
        sr[r] += p;
        Plds[wid][4 * g + r][sub * 16 + n] = f2bf(p);
      }
    }
    #pragma unroll
    for (int off = 1; off <= 8; off <<= 1) {
      #pragma unroll
      for (int r = 0; r < 4; ++r)
        sr[r] += __shfl_xor(sr[r], off);
    }
    #pragma unroll
    for (int r = 0; r < 4; ++r) l[r] = l[r] * corr[r] + sr[r];
    #pragma unroll
    for (int d0 = 0; d0 < 8; ++d0) {
      #pragma unroll
      for (int r = 0; r < 4; ++r) acc[d0][r] *= corr[r];
    }

    // ---- PV: O += P * V ----
    #pragma unroll
    for (int ks = 0; ks < 2; ++ks) {
      bf16x8 a = *(const bf16x8*)&Plds[wid][n][32 * ks + 8 * g];
      #pragma unroll
      for (int d0 = 0; d0 < 8; ++d0) {
        bf16x8 b = *(const bf16x8*)&VTlds[d0 * 16 + n][32 * ks + 8 * g];
        acc[d0] = __builtin_amdgcn_mfma_f32_16x16x32_bf16(a, b, acc[d0], 0, 0, 0);
      }
    }
  }

  // ---- epilogue: normalize and store fp32 ----
  float invl[4];
  #pragma unroll
  for (int r = 0; r < 4; ++r) invl[r] = 1.0f / l[r];
  #pragma unroll
  for (int d0 = 0; d0 < 8; ++d0) {
    #pragma unroll
    for (int r = 0; r < 4; ++r) {
      O[((size_t)(qw + 4 * g + r) * HH + h) * DD + d0 * 16 + n] = acc[d0][r] * invl[r];
    }
  }
}

extern "C" void kernel_launch(void* const* d_in, const int* in_sizes, int n_in,
                              void* d_out, int out_size, void* d_ws, size_t ws_size,
                              hipStream_t stream) {
  const float* Q = (const float*)d_in[0];
  const float* K = (const float*)d_in[1];
  const float* V = (const float*)d_in[2];
  float* O = (float*)d_out;

  const size_t kv_elems = (size_t)HH * SS * DD;   // 4,194,304 ushorts each
  ushort* Kbf = (ushort*)d_ws;
  ushort* VTg = Kbf + kv_elems;                   // 16.8 MB total

  prep_kv<<<dim3(HH * (SS / 64)), 256, 0, stream>>>(K, V, Kbf, VTg);
  attn_fwd<<<dim3((SS / QBLK) * HH), 256, 0, stream>>>(Q, Kbf, VTg, O);
}

// Round 6
// 78.778 us; speedup vs baseline: 1.6787x; 1.6787x over previous
//
#include <hip/hip_runtime.h>
#include <hip/hip_bf16.h>
#include <math.h>

#define SS 2048
#define HH 16
#define DD 128
#define HD (HH*DD)
#define QBLK 64
#define KVBLK 64

typedef __attribute__((ext_vector_type(8))) short bf16x8;
typedef __attribute__((ext_vector_type(4))) float f32x4;

#define EXP2(x) exp2f(x)

__device__ __forceinline__ ushort f2bf(float f) {
  __hip_bfloat16 h = __float2bfloat16(f);
  return __builtin_bit_cast(ushort, h);
}

__device__ __forceinline__ void prefetch_tile(const float* __restrict__ Kbase,
                                              const float* __restrict__ Vbase,
                                              int t0, int tid, int wid, int n, int g,
                                              float4* kreg, float4* vreg) {
  #pragma unroll
  for (int it = 0; it < 8; ++it) {
    int li = tid + it * 256;
    int t  = li >> 5;
    int c4 = (li & 31) << 2;
    kreg[it] = *(const float4*)&Kbase[(size_t)(t0 + t) * HD + c4];
  }
  const int dd0 = wid * 16 + n;
  #pragma unroll
  for (int half = 0; half < 2; ++half) {
    #pragma unroll
    for (int jj = 0; jj < 4; ++jj) {
      const float* vp = &Vbase[(size_t)(t0 + 16 * jj + 4 * g) * HD + (dd0 + 64 * half)];
      vreg[half * 4 + jj] = make_float4(vp[0], vp[HD], vp[2 * HD], vp[3 * HD]);
    }
  }
}

// ---------------------------------------------------------------------------
// Equal-length jobs: pair (p, 31-p) per head. job0 = q-tile p (full, final
// write) + first 16-p tiles of q-tile 31-p (partial). job1 = last 16 tiles
// of q-tile 31-p (partial). Big q-tiles merged by attn_merge.
// ---------------------------------------------------------------------------
__global__ __launch_bounds__(256, 2)
void attn_fwd(const float* __restrict__ Q, const float* __restrict__ K,
              const float* __restrict__ V, float* __restrict__ O,
              float* __restrict__ PO, float* __restrict__ PM,
              float* __restrict__ PL) {
  __shared__ alignas(16) ushort Klds[KVBLK][136];   // 17408 B
  __shared__ alignas(16) ushort VTlds[DD][72];      // 18432 B
  __shared__ alignas(16) ushort Plds[4][16][72];    //  9216 B

  const int tid  = threadIdx.x;
  const int lane = tid & 63;
  const int wid  = tid >> 6;
  const int n    = lane & 15;
  const int g    = lane >> 4;

  const int h     = blockIdx.x & (HH - 1);
  const int job   = blockIdx.x >> 4;     // 0..31
  const int p     = job & 15;
  const int which = job >> 4;            // 0 or 1

  const float SCALE = 1.44269504088896f / sqrtf((float)DD);
  const float* Kbase = K + (size_t)h * DD;
  const float* Vbase = V + (size_t)h * DD;

  const int nph = (which == 0) ? 2 : 1;

  for (int ph = 0; ph < nph; ++ph) {
    int qt_, lo, hi, fin, slot;
    if (which == 0) {
      if (ph == 0) { qt_ = p;      lo = 0;      hi = p + 1;  fin = 1; slot = 0; }
      else         { qt_ = 31 - p; lo = 0;      hi = 16 - p; fin = 0; slot = 0; }
    } else         { qt_ = 31 - p; lo = 16 - p; hi = 32 - p; fin = 0; slot = 1; }

    const int qb = qt_ * QBLK;
    const int qw = qb + 16 * wid;

    // ---- preload Q fragments (A operand), scaled, bf16 ----
    bf16x8 qfrag[4];
    {
      const float* qrow = Q + ((size_t)(qw + n) * HH + h) * DD;
      #pragma unroll
      for (int ks = 0; ks < 4; ++ks) {
        const int d0 = 32 * ks + 8 * g;
        float4 x = *(const float4*)&qrow[d0];
        float4 y = *(const float4*)&qrow[d0 + 4];
        bf16x8 a;
        a[0] = (short)f2bf(x.x * SCALE); a[1] = (short)f2bf(x.y * SCALE);
        a[2] = (short)f2bf(x.z * SCALE); a[3] = (short)f2bf(x.w * SCALE);
        a[4] = (short)f2bf(y.x * SCALE); a[5] = (short)f2bf(y.y * SCALE);
        a[6] = (short)f2bf(y.z * SCALE); a[7] = (short)f2bf(y.w * SCALE);
        qfrag[ks] = a;
      }
    }

    f32x4 acc[8];
    #pragma unroll
    for (int d0 = 0; d0 < 8; ++d0) { acc[d0][0]=0.f; acc[d0][1]=0.f; acc[d0][2]=0.f; acc[d0][3]=0.f; }
    float m[4] = { -INFINITY, -INFINITY, -INFINITY, -INFINITY };
    float l[4] = { 0.f, 0.f, 0.f, 0.f };

    float4 kreg[8], vreg[8];
    prefetch_tile(Kbase, Vbase, lo * KVBLK, tid, wid, n, g, kreg, vreg);

    for (int itile = lo; itile < hi; ++itile) {
      __syncthreads();   // previous tile's LDS fully consumed

      // ---- regs -> LDS (bf16) ----
      #pragma unroll
      for (int it = 0; it < 8; ++it) {
        int li = tid + it * 256;
        int t  = li >> 5;
        int c4 = (li & 31) << 2;
        float4 x = kreg[it];
        ushort4 w;
        w.x = f2bf(x.x); w.y = f2bf(x.y); w.z = f2bf(x.z); w.w = f2bf(x.w);
        *(ushort4*)&Klds[t][c4] = w;
      }
      {
        const int dd0 = wid * 16 + n;
        #pragma unroll
        for (int half = 0; half < 2; ++half) {
          #pragma unroll
          for (int jj = 0; jj < 4; ++jj) {
            float4 x = vreg[half * 4 + jj];
            ushort4 w;
            w.x = f2bf(x.x); w.y = f2bf(x.y); w.z = f2bf(x.z); w.w = f2bf(x.w);
            *(ushort4*)&VTlds[dd0 + 64 * half][16 * jj + 4 * g] = w;
          }
        }
      }
      __syncthreads();   // LDS tile ready

      // ---- prefetch next tile ----
      if (itile + 1 < hi) {
        prefetch_tile(Kbase, Vbase, (itile + 1) * KVBLK, tid, wid, n, g, kreg, vreg);
      }

      const int t0 = itile * KVBLK;

      // ---- QK^T: S[q][t], 16x64 per wave ----
      f32x4 s[4];
      #pragma unroll
      for (int sub = 0; sub < 4; ++sub) { s[sub][0]=0.f; s[sub][1]=0.f; s[sub][2]=0.f; s[sub][3]=0.f; }
      #pragma unroll
      for (int ks = 0; ks < 4; ++ks) {
        #pragma unroll
        for (int sub = 0; sub < 4; ++sub) {
          bf16x8 b = *(const bf16x8*)&Klds[sub * 16 + n][32 * ks + 8 * g];
          s[sub] = __builtin_amdgcn_mfma_f32_16x16x32_bf16(qfrag[ks], b, s[sub], 0, 0, 0);
        }
      }

      // ---- causal mask (diagonal tiles only) ----
      if (t0 + KVBLK - 1 > qw) {
        #pragma unroll
        for (int sub = 0; sub < 4; ++sub) {
          int tg = t0 + sub * 16 + n;
          #pragma unroll
          for (int r = 0; r < 4; ++r) {
            int qg = qw + 4 * g + r;
            if (tg > qg) s[sub][r] = -INFINITY;
          }
        }
      }

      // ---- online softmax (log2 domain) ----
      float mr[4];
      #pragma unroll
      for (int r = 0; r < 4; ++r)
        mr[r] = fmaxf(fmaxf(s[0][r], s[1][r]), fmaxf(s[2][r], s[3][r]));
      #pragma unroll
      for (int off = 1; off <= 8; off <<= 1) {
        #pragma unroll
        for (int r = 0; r < 4; ++r)
          mr[r] = fmaxf(mr[r], __shfl_xor(mr[r], off));
      }
      float corr[4];
      #pragma unroll
      for (int r = 0; r < 4; ++r) {
        float mn = fmaxf(m[r], mr[r]);
        corr[r] = EXP2(m[r] - mn);
        m[r] = mn;
      }
      float sr[4] = { 0.f, 0.f, 0.f, 0.f };
      #pragma unroll
      for (int sub = 0; sub < 4; ++sub) {
        #pragma unroll
        for (int r = 0; r < 4; ++r) {
          float pp = EXP2(s[sub][r] - m[r]);
          sr[r] += pp;
          Plds[wid][4 * g + r][sub * 16 + n] = f2bf(pp);
        }
      }
      #pragma unroll
      for (int off = 1; off <= 8; off <<= 1) {
        #pragma unroll
        for (int r = 0; r < 4; ++r)
          sr[r] += __shfl_xor(sr[r], off);
      }
      #pragma unroll
      for (int r = 0; r < 4; ++r) l[r] = l[r] * corr[r] + sr[r];
      #pragma unroll
      for (int d0 = 0; d0 < 8; ++d0) {
        #pragma unroll
        for (int r = 0; r < 4; ++r) acc[d0][r] *= corr[r];
      }

      // ---- PV ----
      #pragma unroll
      for (int ks = 0; ks < 2; ++ks) {
        bf16x8 a = *(const bf16x8*)&Plds[wid][n][32 * ks + 8 * g];
        #pragma unroll
        for (int d0 = 0; d0 < 8; ++d0) {
          bf16x8 b = *(const bf16x8*)&VTlds[d0 * 16 + n][32 * ks + 8 * g];
          acc[d0] = __builtin_amdgcn_mfma_f32_16x16x32_bf16(a, b, acc[d0], 0, 0, 0);
        }
      }
    }

    // ---- epilogue ----
    if (fin) {
      float invl[4];
      #pragma unroll
      for (int r = 0; r < 4; ++r) invl[r] = 1.0f / l[r];
      #pragma unroll
      for (int d0 = 0; d0 < 8; ++d0) {
        #pragma unroll
        for (int r = 0; r < 4; ++r) {
          O[((size_t)(qw + 4 * g + r) * HH + h) * DD + d0 * 16 + n] = acc[d0][r] * invl[r];
        }
      }
    } else {
      const int pidx = (h * 16 + (qt_ - 16)) * 2 + slot;
      float* po = PO + (size_t)pidx * (QBLK * DD);
      #pragma unroll
      for (int d0 = 0; d0 < 8; ++d0) {
        #pragma unroll
        for (int r = 0; r < 4; ++r) {
          po[(16 * wid + 4 * g + r) * DD + d0 * 16 + n] = acc[d0][r];
        }
      }
      if (n == 0) {
        #pragma unroll
        for (int r = 0; r < 4; ++r) {
          PM[(size_t)pidx * QBLK + 16 * wid + 4 * g + r] = m[r];
          PL[(size_t)pidx * QBLK + 16 * wid + 4 * g + r] = l[r];
        }
      }
    }
  }
}

// ---------------------------------------------------------------------------
// Merge the 2 partials of each big q-tile (qt >= 16).
// ---------------------------------------------------------------------------
__global__ __launch_bounds__(256, 8)
void attn_merge(const float* __restrict__ PO, const float* __restrict__ PM,
                const float* __restrict__ PL, float* __restrict__ O) {
  const int bx  = blockIdx.x;        // 256
  const int h   = bx & 15;
  const int qtb = bx >> 4;           // 0..15
  const int qt  = 16 + qtb;
  const int tid = threadIdx.x;
  const int r   = tid >> 2;          // 0..63
  const int dc  = (tid & 3) << 5;    // 0,32,64,96

  const int i0 = (h * 16 + qtb) * 2;
  const int i1 = i0 + 1;
  float m0 = PM[(size_t)i0 * QBLK + r], m1 = PM[(size_t)i1 * QBLK + r];
  float l0 = PL[(size_t)i0 * QBLK + r], l1 = PL[(size_t)i1 * QBLK + r];
  float M  = fmaxf(m0, m1);
  float w0 = EXP2(m0 - M), w1 = EXP2(m1 - M);
  float inv = 1.0f / (l0 * w0 + l1 * w1);
  w0 *= inv; w1 *= inv;

  const float* a = PO + (size_t)i0 * (QBLK * DD) + r * DD + dc;
  const float* b = PO + (size_t)i1 * (QBLK * DD) + r * DD + dc;
  float* op = O + ((size_t)(qt * QBLK + r) * HH + h) * DD + dc;
  #pragma unroll
  for (int k = 0; k < 8; ++k) {
    float4 x = *(const float4*)&a[4 * k];
    float4 y = *(const float4*)&b[4 * k];
    float4 o;
    o.x = x.x * w0 + y.x * w1;
    o.y = x.y * w0 + y.y * w1;
    o.z = x.z * w0 + y.z * w1;
    o.w = x.w * w0 + y.w * w1;
    *(float4*)&op[4 * k] = o;
  }
}

extern "C" void kernel_launch(void* const* d_in, const int* in_sizes, int n_in,
                              void* d_out, int out_size, void* d_ws, size_t ws_size,
                              hipStream_t stream) {
  const float* Q = (const float*)d_in[0];
  const float* K = (const float*)d_in[1];
  const float* V = (const float*)d_in[2];
  float* O = (float*)d_out;

  const size_t po_elems = (size_t)512 * QBLK * DD;   // 4,194,304 floats = 16.8 MB
  const size_t ml_elems = (size_t)512 * QBLK;
  float* PO = (float*)d_ws;
  float* PM = PO + po_elems;
  float* PL = PM + ml_elems;

  attn_fwd<<<dim3(512), 256, 0, stream>>>(Q, K, V, O, PO, PM, PL);
  attn_merge<<<dim3(256), 256, 0, stream>>>(PO, PM, PL, O);
}